// Round 1
// baseline (660.290 us; speedup 1.0000x reference)
//
#include <hip/hip_runtime.h>

#define BB 64
#define TT 512
#define HH 1024
#define CC 21

// ---------------------------------------------------------------------------
// K1: logits[b,t,c] = sum_h seq[b,t,h] * W[h,c] + bias[c]
// One row (b*T+t) per thread. x loads are float4; W reads are wave-uniform
// (h0 loop counter + unrolled c) so they lower to scalar loads on the s-pipe.
// ---------------------------------------------------------------------------
__global__ __launch_bounds__(64) void logits_kernel(
    const float* __restrict__ seq,   // [B*T, H]
    const float* __restrict__ W,     // [H, C]
    const float* __restrict__ bias,  // [C]
    float* __restrict__ logits)      // [B*T, C]
{
    int row = blockIdx.x * 64 + threadIdx.x;   // grid sized exactly: 512 blocks
    const float* x = seq + (size_t)row * HH;

    float acc[CC];
#pragma unroll
    for (int c = 0; c < CC; ++c) acc[c] = 0.f;

    for (int h0 = 0; h0 < HH; h0 += 4) {
        float4 xv = *reinterpret_cast<const float4*>(x + h0);
#pragma unroll
        for (int c = 0; c < CC; ++c) {
            acc[c] += xv.x * W[(h0 + 0) * CC + c]
                    + xv.y * W[(h0 + 1) * CC + c]
                    + xv.z * W[(h0 + 2) * CC + c]
                    + xv.w * W[(h0 + 3) * CC + c];
        }
    }

#pragma unroll
    for (int c = 0; c < CC; ++c)
        logits[(size_t)row * CC + c] = acc[c] + bias[c];
}

// ---------------------------------------------------------------------------
// K2: Viterbi forward + backtrack, one block (1 wave) per batch.
// lane = class c (lanes 21..63 ride along masked). State broadcast via
// __shfl with constant source lane. bp table kept in LDS (u8), backtrack is
// a uniform LDS pointer chase; lanes 0..20 write the one-hot row each step.
// Masking matches tfa.crf_decode: valid = (t < seq_len); frozen state and
// identity backpointers on invalid steps. argmax = first-max (strict >).
// ---------------------------------------------------------------------------
__global__ __launch_bounds__(64) void viterbi_kernel(
    const float* __restrict__ logits,  // [B, T, C]
    const int* __restrict__ mask,      // [B, T]
    const float* __restrict__ trans,   // [C, C]
    float* __restrict__ onehot)        // [B, T, C]
{
    __shared__ unsigned char bp_lds[(TT - 1) * CC];  // 10731 B

    const int b    = blockIdx.x;
    const int lane = threadIdx.x;
    const int c    = lane;
    const bool act = (c < CC);

    // seq_len = sum of mask row (wave reduction)
    int sl = 0;
#pragma unroll
    for (int k = 0; k < TT / 64; ++k) sl += mask[b * TT + k * 64 + lane];
#pragma unroll
    for (int o = 32; o > 0; o >>= 1) sl += __shfl_xor(sl, o);

    // transitions column c: tcol[cp] = trans[cp, c]
    float tcol[CC];
#pragma unroll
    for (int cp = 0; cp < CC; ++cp)
        tcol[cp] = act ? trans[cp * CC + c] : 0.f;

    const float* lb = logits + (size_t)b * TT * CC;
    float state = act ? lb[c] : -1e30f;

    for (int t = 1; t < TT; ++t) {
        float logit_c = act ? lb[t * CC + c] : 0.f;

        float best = 0.f;
        int bi = 0;
#pragma unroll
        for (int cp = 0; cp < CC; ++cp) {
            float s = __shfl(state, cp);     // constant lane -> v_readlane
            float score = s + tcol[cp];
            if (cp == 0) {
                best = score; bi = 0;
            } else {
                bool gt = score > best;      // strict >: first-max semantics
                best = gt ? score : best;
                bi   = gt ? cp : bi;
            }
        }

        bool valid = (t < sl);
        float ns = best + logit_c;
        state = (valid && act) ? ns : state;
        int bpv = valid ? bi : c;            // identity bp on invalid steps
        if (act) bp_lds[(t - 1) * CC + c] = (unsigned char)bpv;
    }

    __syncthreads();

    // last_tag = argmax_c final_state (first-max)
    int last = 0;
    {
        float bv = __shfl(state, 0);
#pragma unroll
        for (int cp = 1; cp < CC; ++cp) {
            float v = __shfl(state, cp);
            bool gt = v > bv;
            bv   = gt ? v : bv;
            last = gt ? cp : last;
        }
    }

    // backtrack: tags[t] = bp_{t+1}[tags[t+1]]; write one-hot rows
    float* ob = onehot + (size_t)b * TT * CC;
    int tag = last;  // uniform across lanes
    for (int t = TT - 1; t >= 0; --t) {
        if (act) ob[t * CC + c] = (c == tag) ? 1.f : 0.f;
        if (t > 0) tag = bp_lds[(t - 1) * CC + tag];  // uniform LDS read
    }
}

extern "C" void kernel_launch(void* const* d_in, const int* in_sizes, int n_in,
                              void* d_out, int out_size, void* d_ws, size_t ws_size,
                              hipStream_t stream) {
    const float* seq   = (const float*)d_in[0];  // [B,T,H] f32
    const int*   msk   = (const int*)d_in[1];    // [B,T] i32
    const float* W     = (const float*)d_in[2];  // [H,C] f32
    const float* bias  = (const float*)d_in[3];  // [C] f32
    const float* trans = (const float*)d_in[4];  // [C,C] f32

    float* onehot_out = (float*)d_out;                    // output 0: [B,T,C]
    float* logits_out = onehot_out + (size_t)BB * TT * CC; // output 1: [B,T,C]

    logits_kernel<<<(BB * TT) / 64, 64, 0, stream>>>(seq, W, bias, logits_out);
    viterbi_kernel<<<BB, 64, 0, stream>>>(logits_out, msk, trans, onehot_out);
}

// Round 2
// 405.040 us; speedup vs baseline: 1.6302x; 1.6302x over previous
//
#include <hip/hip_runtime.h>
#include <stdint.h>

#define BB 64
#define TT 512
#define HH 1024
#define CC 21

#define GAS __attribute__((address_space(1)))
#define LAS __attribute__((address_space(3)))

// async global->LDS, 16B per lane, dest = uniform base + lane*16
__device__ __forceinline__ void gll16(const void* g, void* l) {
    __builtin_amdgcn_global_load_lds((const GAS uint32_t*)g, (LAS uint32_t*)l, 16, 0, 0);
}

// ---------------------------------------------------------------------------
// K1: logits = seq @ W + b.  Block = 1 wave = 64 rows (lane = row).
// x staged global->LDS via global_load_lds (double-buffered, 128-h chunks).
// LDS layout: row r's 32 float4s live at slots r*32 + (h4 ^ (r&7))  (XOR
// swizzle applied on the GLOBAL source address; LDS dest stays linear).
// Compute: lane reads own row from LDS (ds_read_b128, structural-min banks),
// W[h][c] is wave-uniform -> scalar loads on the s-pipe.
// ---------------------------------------------------------------------------
__global__ __launch_bounds__(64) void logits_kernel(
    const float* __restrict__ seq,   // [B*T, H]
    const float* __restrict__ W,     // [H, C]
    const float* __restrict__ bias,  // [C]
    float* __restrict__ logits)      // [B*T, C]
{
    __shared__ float4 xs[2][2048];   // 2 x 32KB
    const int l    = threadIdx.x;
    const int row0 = blockIdx.x * 64;

    float acc[CC];
#pragma unroll
    for (int c = 0; c < CC; ++c) acc[c] = 0.f;

    auto stage = [&](int ch, int bb) {
#pragma unroll
        for (int it = 0; it < 32; ++it) {
            int r  = it * 2 + (l >> 5);          // slot s = it*64+l; r = s>>5
            int h4 = (l & 31) ^ (r & 7);         // pre-swizzled global source
            const float* g = seq + (size_t)(row0 + r) * HH + ch * 128 + h4 * 4;
            gll16(g, &xs[bb][it * 64]);          // lane lands at slot it*64+lane
        }
    };

    auto compute = [&](int ch, int bb) {
        const float4* xb = (const float4*)&xs[bb][0];
        const int base = l * 32, sw = l & 7;
#pragma unroll
        for (int i = 0; i < 32; ++i) {
            float4 xv = xb[base + (i ^ sw)];
            const float* Wh = W + (size_t)(ch * 128 + i * 4) * CC;  // uniform -> s_load
#pragma unroll
            for (int c = 0; c < CC; ++c) {
                acc[c] += xv.x * Wh[c]
                        + xv.y * Wh[CC + c]
                        + xv.z * Wh[2 * CC + c]
                        + xv.w * Wh[3 * CC + c];
            }
        }
    };

    stage(0, 0);
    asm volatile("s_waitcnt vmcnt(0)" ::: "memory");
    __syncthreads();
    int bb = 0;
#pragma unroll 1
    for (int ch = 0; ch < 8; ++ch) {
        if (ch < 7) stage(ch + 1, bb ^ 1);   // loads fly during compute
        compute(ch, bb);
        asm volatile("s_waitcnt vmcnt(0)" ::: "memory");
        __syncthreads();
        bb ^= 1;
    }

    float* orow = logits + (size_t)(row0 + l) * CC;
#pragma unroll
    for (int c = 0; c < CC; ++c) orow[c] = acc[c] + bias[c];
}

// ---------------------------------------------------------------------------
// K2: Viterbi fwd + backtrack. Block = 1 wave per batch, lane = class.
// Batch logits staged to LDS once (coalesced). Forward runs only seq_len
// steps (reference freezes state for t >= seq_len; bps there are identity).
// Step: 21 readlane broadcasts + fmax tree + descending eq-scan (first-max).
// Backtrack: uniform u8 LDS chase; positions >= sl-1 are all last_tag.
// ---------------------------------------------------------------------------
__global__ __launch_bounds__(64) void viterbi_kernel(
    const float* __restrict__ logits,  // [B, T, C]
    const int* __restrict__ mask,      // [B, T]
    const float* __restrict__ trans,   // [C, C]
    float* __restrict__ onehot)        // [B, T, C]
{
    __shared__ __align__(16) float lg[TT * CC];                 // 43008 B
    __shared__ unsigned char bp[(TT - 1) * CC];                 // 10731 B

    const int b   = blockIdx.x;
    const int l   = threadIdx.x;
    const bool act = (l < CC);
    const int cc  = act ? l : 0;

    // stage logits[b] -> LDS (2688 float4 = 42 iters * 64 lanes)
    const float* lb = logits + (size_t)b * TT * CC;
#pragma unroll
    for (int it = 0; it < 42; ++it)
        gll16(lb + (size_t)(it * 64 + l) * 4, &lg[it * 256]);

    // seq_len (uniform per block)
    int sl = 0;
#pragma unroll
    for (int k = 0; k < 8; ++k) sl += mask[b * TT + k * 64 + l];
#pragma unroll
    for (int o = 32; o > 0; o >>= 1) sl += __shfl_xor(sl, o);

    float tcol[CC];
#pragma unroll
    for (int cp = 0; cp < CC; ++cp) tcol[cp] = trans[cp * CC + cc];

    asm volatile("s_waitcnt vmcnt(0)" ::: "memory");
    __syncthreads();

    float st = lg[cc];   // lane c holds state[c]

#define RL(x, lane) __uint_as_float(__builtin_amdgcn_readlane(__float_as_uint(x), (lane)))

    for (int t = 1; t < sl; ++t) {
        float lgt = lg[t * CC + cc];     // off the dependency chain, prefetchable
        float sc[CC];
#pragma unroll
        for (int cp = 0; cp < CC; ++cp) sc[cp] = RL(st, cp) + tcol[cp];

        // fmax tree 21 -> 1 (max selection is exact)
        float a0 = fmaxf(sc[0], sc[1]),  a1 = fmaxf(sc[2], sc[3]);
        float a2 = fmaxf(sc[4], sc[5]),  a3 = fmaxf(sc[6], sc[7]);
        float a4 = fmaxf(sc[8], sc[9]),  a5 = fmaxf(sc[10], sc[11]);
        float a6 = fmaxf(sc[12], sc[13]), a7 = fmaxf(sc[14], sc[15]);
        float a8 = fmaxf(sc[16], sc[17]), a9 = fmaxf(sc[18], sc[19]);
        float b0 = fmaxf(fmaxf(a0, a1), a2);
        float b1 = fmaxf(fmaxf(a3, a4), a5);
        float b2 = fmaxf(fmaxf(a6, a7), a8);
        float b3 = fmaxf(a9, sc[20]);
        float best = fmaxf(fmaxf(b0, b1), fmaxf(b2, b3));

        // first-max index: descending scan, lowest cp wins ties
        int bi = CC - 1;
#pragma unroll
        for (int cp = CC - 2; cp >= 0; --cp) bi = (sc[cp] == best) ? cp : bi;

        st = best + lgt;                       // lanes >= CC compute garbage, never read
        if (act) bp[(t - 1) * CC + l] = (unsigned char)bi;
    }

    // last_tag = first-max over final state
    float fs[CC];
#pragma unroll
    for (int cp = 0; cp < CC; ++cp) fs[cp] = RL(st, cp);
    float c0 = fmaxf(fs[0], fs[1]),  c1 = fmaxf(fs[2], fs[3]);
    float c2 = fmaxf(fs[4], fs[5]),  c3 = fmaxf(fs[6], fs[7]);
    float c4 = fmaxf(fs[8], fs[9]),  c5 = fmaxf(fs[10], fs[11]);
    float c6 = fmaxf(fs[12], fs[13]), c7 = fmaxf(fs[14], fs[15]);
    float c8 = fmaxf(fs[16], fs[17]), c9 = fmaxf(fs[18], fs[19]);
    float d0 = fmaxf(fmaxf(c0, c1), c2);
    float d1 = fmaxf(fmaxf(c3, c4), c5);
    float d2 = fmaxf(fmaxf(c6, c7), c8);
    float d3 = fmaxf(c9, fs[20]);
    float fbest = fmaxf(fmaxf(d0, d1), fmaxf(d2, d3));
    int last = CC - 1;
#pragma unroll
    for (int cp = CC - 2; cp >= 0; --cp) last = (fs[cp] == fbest) ? cp : last;

    __syncthreads();

    // one-hot writes
    float* ob = onehot + (size_t)b * TT * CC;
    const int pstart = (sl >= 1) ? (sl - 1) : 0;
    for (int p = pstart; p < TT; ++p)
        if (act) ob[(size_t)p * CC + l] = (l == last) ? 1.f : 0.f;

    int tag = last;
    for (int p = pstart - 1; p >= 0; --p) {
        tag = bp[p * CC + tag];                 // uniform LDS chase
        if (act) ob[(size_t)p * CC + l] = (l == tag) ? 1.f : 0.f;
    }
#undef RL
}

extern "C" void kernel_launch(void* const* d_in, const int* in_sizes, int n_in,
                              void* d_out, int out_size, void* d_ws, size_t ws_size,
                              hipStream_t stream) {
    const float* seq   = (const float*)d_in[0];  // [B,T,H] f32
    const int*   msk   = (const int*)d_in[1];    // [B,T] i32
    const float* W     = (const float*)d_in[2];  // [H,C] f32
    const float* bias  = (const float*)d_in[3];  // [C] f32
    const float* trans = (const float*)d_in[4];  // [C,C] f32

    float* onehot_out = (float*)d_out;                     // output 0: [B,T,C]
    float* logits_out = onehot_out + (size_t)BB * TT * CC; // output 1: [B,T,C]

    logits_kernel<<<(BB * TT) / 64, 64, 0, stream>>>(seq, W, bias, logits_out);
    viterbi_kernel<<<BB, 64, 0, stream>>>(logits_out, msk, trans, onehot_out);
}

// Round 3
// 216.836 us; speedup vs baseline: 3.0451x; 1.8680x over previous
//
#include <hip/hip_runtime.h>
#include <stdint.h>

#define BB 64
#define TT 512
#define HH 1024
#define CC 21

// ---------------------------------------------------------------------------
// K1: logits = seq @ W + b.  512 blocks x 256 threads.
// Block = 64 rows [bid*64, +64). Wave w (t>>6) owns h-quarter [w*256,+256),
// 16 chunks of 16 h. Lane l = row. Per chunk:
//   - X staged global->reg->LDS transposed: [s][r] so compute ds_read_b128 is
//     lane-consecutive (conflict-free); global side reads 64B/row contiguous.
//   - W slab (16h x 21) staged to LDS rows padded to 24 floats -> aligned
//     b128 UNIFORM reads = broadcast (off the scalar pipe -> no s_load stalls).
//   - double-buffered; loads for ch+1 issued before compute(ch) (T14).
// Epilogue: waves 1..3 write partial acc[21] to LDS; wave 0 sums + bias + store.
// ---------------------------------------------------------------------------
__global__ __launch_bounds__(256) void logits_kernel(
    const float* __restrict__ seq,   // [B*T, H]
    const float* __restrict__ W,     // [H, C]
    const float* __restrict__ bias,  // [C]
    float* __restrict__ logits)      // [B*T, C]
{
    __shared__ float4 xs[4][2][256];      // 32 KB: [wave][buf][s*64+r]
    __shared__ float  wt[4][2][16 * 24];  // 12 KB: [wave][buf][h*24+c]
    __shared__ float  comb[3][64][22];    // 16.5 KB combine scratch

    const int t = threadIdx.x;
    const int w = t >> 6;          // h-quarter
    const int l = t & 63;          // row within block
    const int row0 = blockIdx.x * 64;
    const int hbase = w * 256;

    float acc[CC];
#pragma unroll
    for (int c = 0; c < CC; ++c) acc[c] = 0.f;

    float4 xr[4];
    float  wr[6];

    auto issue = [&](int ch) {
        const int h0 = hbase + ch * 16;
#pragma unroll
        for (int k = 0; k < 4; ++k) {
            int r = 16 * k + (l >> 2), s = l & 3;
            xr[k] = *(const float4*)(seq + (size_t)(row0 + r) * HH + h0 + s * 4);
        }
        const float* wg = W + (size_t)h0 * CC;   // 336 contiguous floats
#pragma unroll
        for (int i = 0; i < 6; ++i) {
            int j = i * 64 + l;
            wr[i] = (j < 16 * CC) ? wg[j] : 0.f;
        }
    };

    auto commit = [&](int buf) {
#pragma unroll
        for (int k = 0; k < 4; ++k)
            xs[w][buf][(l & 3) * 64 + 16 * k + (l >> 2)] = xr[k];
#pragma unroll
        for (int i = 0; i < 6; ++i) {
            int j = i * 64 + l;
            if (j < 16 * CC) wt[w][buf][(j / CC) * 24 + (j % CC)] = wr[i];
        }
    };

    auto compute = [&](int buf) {
        const float4* xb = xs[w][buf];
        const float*  wb = wt[w][buf];
#pragma unroll
        for (int g = 0; g < 4; ++g) {
            float4 xv = xb[g * 64 + l];          // lane-consecutive b128
#pragma unroll
            for (int j = 0; j < 4; ++j) {
                const float4* wrow = (const float4*)(wb + (g * 4 + j) * 24);
                float xc = (&xv.x)[j];
#pragma unroll
                for (int r5 = 0; r5 < 6; ++r5) {  // uniform addr -> broadcast
                    float4 w4 = wrow[r5];
                    int c0 = r5 * 4;
                    acc[c0] += xc * w4.x;
                    if (c0 + 1 < CC) acc[c0 + 1] += xc * w4.y;
                    if (c0 + 2 < CC) acc[c0 + 2] += xc * w4.z;
                    if (c0 + 3 < CC) acc[c0 + 3] += xc * w4.w;
                }
            }
        }
    };

    issue(0);
    commit(0);
    __syncthreads();
    int buf = 0;
#pragma unroll 1
    for (int ch = 0; ch < 16; ++ch) {
        if (ch < 15) issue(ch + 1);    // loads fly during compute
        compute(buf);
        if (ch < 15) commit(buf ^ 1);  // other buffer, own wave's region
        __syncthreads();
        buf ^= 1;
    }

    // combine h-quarters
    if (w > 0) {
#pragma unroll
        for (int c = 0; c < CC; ++c) comb[w - 1][l][c] = acc[c];
    }
    __syncthreads();
    if (w == 0) {
        float* orow = logits + (size_t)(row0 + l) * CC;
#pragma unroll
        for (int c = 0; c < CC; ++c)
            orow[c] = acc[c] + comb[0][l][c] + comb[1][l][c] + comb[2][l][c] + bias[c];
    }
}

// ---------------------------------------------------------------------------
// K2: Viterbi fwd + backtrack (unchanged from round 2 — ~15-25us).
// ---------------------------------------------------------------------------
#define GAS __attribute__((address_space(1)))
#define LAS __attribute__((address_space(3)))
__device__ __forceinline__ void gll16(const void* g, void* l) {
    __builtin_amdgcn_global_load_lds((const GAS uint32_t*)g, (LAS uint32_t*)l, 16, 0, 0);
}

__global__ __launch_bounds__(64) void viterbi_kernel(
    const float* __restrict__ logits,  // [B, T, C]
    const int* __restrict__ mask,      // [B, T]
    const float* __restrict__ trans,   // [C, C]
    float* __restrict__ onehot)        // [B, T, C]
{
    __shared__ __align__(16) float lg[TT * CC];
    __shared__ unsigned char bp[(TT - 1) * CC];

    const int b = blockIdx.x;
    const int l = threadIdx.x;
    const bool act = (l < CC);
    const int cc = act ? l : 0;

    const float* lb = logits + (size_t)b * TT * CC;
#pragma unroll
    for (int it = 0; it < 42; ++it)
        gll16(lb + (size_t)(it * 64 + l) * 4, &lg[it * 256]);

    int sl = 0;
#pragma unroll
    for (int k = 0; k < 8; ++k) sl += mask[b * TT + k * 64 + l];
#pragma unroll
    for (int o = 32; o > 0; o >>= 1) sl += __shfl_xor(sl, o);

    float tcol[CC];
#pragma unroll
    for (int cp = 0; cp < CC; ++cp) tcol[cp] = trans[cp * CC + cc];

    asm volatile("s_waitcnt vmcnt(0)" ::: "memory");
    __syncthreads();

    float st = lg[cc];

#define RL(x, lane) __uint_as_float(__builtin_amdgcn_readlane(__float_as_uint(x), (lane)))

    for (int t = 1; t < sl; ++t) {
        float lgt = lg[t * CC + cc];
        float sc[CC];
#pragma unroll
        for (int cp = 0; cp < CC; ++cp) sc[cp] = RL(st, cp) + tcol[cp];

        float a0 = fmaxf(sc[0], sc[1]),  a1 = fmaxf(sc[2], sc[3]);
        float a2 = fmaxf(sc[4], sc[5]),  a3 = fmaxf(sc[6], sc[7]);
        float a4 = fmaxf(sc[8], sc[9]),  a5 = fmaxf(sc[10], sc[11]);
        float a6 = fmaxf(sc[12], sc[13]), a7 = fmaxf(sc[14], sc[15]);
        float a8 = fmaxf(sc[16], sc[17]), a9 = fmaxf(sc[18], sc[19]);
        float b0 = fmaxf(fmaxf(a0, a1), a2);
        float b1 = fmaxf(fmaxf(a3, a4), a5);
        float b2 = fmaxf(fmaxf(a6, a7), a8);
        float b3 = fmaxf(a9, sc[20]);
        float best = fmaxf(fmaxf(b0, b1), fmaxf(b2, b3));

        int bi = CC - 1;
#pragma unroll
        for (int cp = CC - 2; cp >= 0; --cp) bi = (sc[cp] == best) ? cp : bi;

        st = best + lgt;
        if (act) bp[(t - 1) * CC + l] = (unsigned char)bi;
    }

    float fs[CC];
#pragma unroll
    for (int cp = 0; cp < CC; ++cp) fs[cp] = RL(st, cp);
    float c0 = fmaxf(fs[0], fs[1]),  c1 = fmaxf(fs[2], fs[3]);
    float c2 = fmaxf(fs[4], fs[5]),  c3 = fmaxf(fs[6], fs[7]);
    float c4 = fmaxf(fs[8], fs[9]),  c5 = fmaxf(fs[10], fs[11]);
    float c6 = fmaxf(fs[12], fs[13]), c7 = fmaxf(fs[14], fs[15]);
    float c8 = fmaxf(fs[16], fs[17]), c9 = fmaxf(fs[18], fs[19]);
    float d0 = fmaxf(fmaxf(c0, c1), c2);
    float d1 = fmaxf(fmaxf(c3, c4), c5);
    float d2 = fmaxf(fmaxf(c6, c7), c8);
    float d3 = fmaxf(c9, fs[20]);
    float fbest = fmaxf(fmaxf(d0, d1), fmaxf(d2, d3));
    int last = CC - 1;
#pragma unroll
    for (int cp = CC - 2; cp >= 0; --cp) last = (fs[cp] == fbest) ? cp : last;

    __syncthreads();

    float* ob = onehot + (size_t)b * TT * CC;
    const int pstart = (sl >= 1) ? (sl - 1) : 0;
    for (int p = pstart; p < TT; ++p)
        if (act) ob[(size_t)p * CC + l] = (l == last) ? 1.f : 0.f;

    int tag = last;
    for (int p = pstart - 1; p >= 0; --p) {
        tag = bp[p * CC + tag];
        if (act) ob[(size_t)p * CC + l] = (l == tag) ? 1.f : 0.f;
    }
#undef RL
}

extern "C" void kernel_launch(void* const* d_in, const int* in_sizes, int n_in,
                              void* d_out, int out_size, void* d_ws, size_t ws_size,
                              hipStream_t stream) {
    const float* seq   = (const float*)d_in[0];  // [B,T,H] f32
    const int*   msk   = (const int*)d_in[1];    // [B,T] i32
    const float* W     = (const float*)d_in[2];  // [H,C] f32
    const float* bias  = (const float*)d_in[3];  // [C] f32
    const float* trans = (const float*)d_in[4];  // [C,C] f32

    float* onehot_out = (float*)d_out;                     // output 0: [B,T,C]
    float* logits_out = onehot_out + (size_t)BB * TT * CC; // output 1: [B,T,C]

    logits_kernel<<<512, 256, 0, stream>>>(seq, W, bias, logits_out);
    viterbi_kernel<<<BB, 64, 0, stream>>>(logits_out, msk, trans, onehot_out);
}

// Round 4
// 149.363 us; speedup vs baseline: 4.4207x; 1.4517x over previous
//
#include <hip/hip_runtime.h>
#include <stdint.h>

#define BB 64
#define TT 512
#define HH 1024
#define CC 21

#define GAS __attribute__((address_space(1)))
#define LAS __attribute__((address_space(3)))
// async global->LDS, 16B per lane, dest = wave-uniform base + lane*16
__device__ __forceinline__ void gll16(const void* g, void* l) {
    __builtin_amdgcn_global_load_lds((const GAS uint32_t*)g, (LAS uint32_t*)l, 16, 0, 0);
}

#define RL(x, lane) __uint_as_float(__builtin_amdgcn_readlane(__float_as_uint(x), (lane)))

// ---------------------------------------------------------------------------
// K1: logits = seq @ W + b.  512 blocks x 256 threads, wave w owns h-quarter.
// Round-3 structure, but NO per-chunk barriers (each wave only touches its own
// xs[w]/wt[w] double-buffer -> pure per-wave program-order deps), and the
// combine scratch is aliased onto xs after a single barrier.
// ---------------------------------------------------------------------------
__global__ __launch_bounds__(256) void logits_kernel(
    const float* __restrict__ seq,   // [B*T, H]
    const float* __restrict__ W,     // [H, C]
    const float* __restrict__ bias,  // [C]
    float* __restrict__ logits)      // [B*T, C]
{
    __shared__ float4 xs[4][2][256];      // 32 KB: [wave][buf][s*64+r]
    __shared__ float  wt[4][2][16 * 24];  // 12 KB: [wave][buf][h*24+c]

    const int t = threadIdx.x;
    const int w = t >> 6;          // h-quarter
    const int l = t & 63;          // row within block
    const int row0 = blockIdx.x * 64;
    const int hbase = w * 256;

    float acc[CC];
#pragma unroll
    for (int c = 0; c < CC; ++c) acc[c] = 0.f;

    float4 xr[4];
    float  wr[6];

    auto issue = [&](int ch) {
        const int h0 = hbase + ch * 16;
#pragma unroll
        for (int k = 0; k < 4; ++k) {
            int r = 16 * k + (l >> 2), s = l & 3;
            xr[k] = *(const float4*)(seq + (size_t)(row0 + r) * HH + h0 + s * 4);
        }
        const float* wg = W + (size_t)h0 * CC;   // 336 contiguous floats
#pragma unroll
        for (int i = 0; i < 6; ++i) {
            int j = i * 64 + l;
            wr[i] = (j < 16 * CC) ? wg[j] : 0.f;
        }
    };

    auto commit = [&](int buf) {
#pragma unroll
        for (int k = 0; k < 4; ++k)
            xs[w][buf][(l & 3) * 64 + 16 * k + (l >> 2)] = xr[k];
#pragma unroll
        for (int i = 0; i < 6; ++i) {
            int j = i * 64 + l;
            if (j < 16 * CC) wt[w][buf][(j / CC) * 24 + (j % CC)] = wr[i];
        }
    };

    auto compute = [&](int buf) {
        const float4* xb = xs[w][buf];
        const float*  wb = wt[w][buf];
#pragma unroll
        for (int g = 0; g < 4; ++g) {
            float4 xv = xb[g * 64 + l];          // lane-consecutive b128
#pragma unroll
            for (int j = 0; j < 4; ++j) {
                const float4* wrow = (const float4*)(wb + (g * 4 + j) * 24);
                float xc = (&xv.x)[j];
#pragma unroll
                for (int r5 = 0; r5 < 6; ++r5) {  // uniform addr -> broadcast
                    float4 w4 = wrow[r5];
                    int c0 = r5 * 4;
                    acc[c0] += xc * w4.x;
                    if (c0 + 1 < CC) acc[c0 + 1] += xc * w4.y;
                    if (c0 + 2 < CC) acc[c0 + 2] += xc * w4.z;
                    if (c0 + 3 < CC) acc[c0 + 3] += xc * w4.w;
                }
            }
        }
    };

    issue(0);
    commit(0);
    int buf = 0;
#pragma unroll 1
    for (int ch = 0; ch < 16; ++ch) {
        if (ch < 15) issue(ch + 1);    // loads fly during compute
        compute(buf);
        if (ch < 15) commit(buf ^ 1);  // own wave's region; no barrier needed
        buf ^= 1;
    }

    // combine h-quarters; scratch aliased onto xs (16.9KB <= 32KB), barrier-guarded
    __syncthreads();
    float* comb = (float*)&xs[0][0][0];
    if (w > 0) {
        float* cr = comb + ((w - 1) * 64 + l) * 22;
#pragma unroll
        for (int c = 0; c < CC; ++c) cr[c] = acc[c];
    }
    __syncthreads();
    if (w == 0) {
        const float* p0 = comb + (size_t)l * 22;
        const float* p1 = comb + (size_t)(64 + l) * 22;
        const float* p2 = comb + (size_t)(128 + l) * 22;
        float* orow = logits + (size_t)(row0 + l) * CC;
#pragma unroll
        for (int c = 0; c < CC; ++c)
            orow[c] = acc[c] + p0[c] + p1[c] + p2[c] + bias[c];
    }
}

// ---------------------------------------------------------------------------
// K2: Viterbi. One block (256 threads) per batch. Wave 0 runs the serial
// forward scan with a MINIMAL chain (21 readlane + 21 add + max3 tree + add),
// storing only the state vector per step. Backpointers are recomputed in
// parallel afterwards (bit-exact: same st+tcol floats, strict-> first-max).
// Backtrack is parallelized via 8 chunked candidate pointer-maps (integer,
// exact). One-hot written by 252 threads.
// ---------------------------------------------------------------------------
__global__ __launch_bounds__(256) void viterbi_kernel(
    const float* __restrict__ logits,  // [B, T, C]
    const int* __restrict__ mask,      // [B, T]
    const float* __restrict__ trans,   // [C, C]
    float* __restrict__ onehot)        // [B, T, C]
{
    __shared__ __align__(16) float lg[(TT + 1) * CC];   // 43092 B (+1 row: prefetch pad)
    __shared__ float stS[TT * CC];                      // 43008 B state history
    __shared__ float trL[CC * CC];                      // 1764 B transitions
    __shared__ unsigned char bp[TT * CC];               // 10752 B backpointers
    __shared__ unsigned char tagl[TT];                  // 512 B decoded tags
    __shared__ unsigned char mapl[8 * CC];              // chunk maps
    __shared__ unsigned char bnd[9];                    // boundary tags

    const int tid = threadIdx.x;
    const int w = tid >> 6;
    const int l = tid & 63;
    const int b = blockIdx.x;

    // stage logits[b] -> LDS (42 gll16 iters split across 4 waves)
    const float* lb = logits + (size_t)b * TT * CC;
    for (int i = w; i < 42; i += 4)
        gll16(lb + (size_t)(i * 64 + l) * 4, &lg[i * 256]);

    // stage transitions -> LDS
    for (int j = tid; j < CC * CC; j += 256) trL[j] = trans[j];

    // seq_len (redundant per wave; uniform)
    int sl = 0;
#pragma unroll
    for (int k = 0; k < 8; ++k) sl += mask[b * TT + k * 64 + l];
#pragma unroll
    for (int o = 32; o > 0; o >>= 1) sl += __shfl_xor(sl, o);
    const int idstart = (sl >= 1) ? (sl - 1) : 0;

    asm volatile("s_waitcnt vmcnt(0)" ::: "memory");
    __syncthreads();

    if (w == 0) {
        // ---- forward scan: minimal serial chain ----
        const bool act = (l < CC);
        const int cc = act ? l : 0;
        float tcol[CC];
#pragma unroll
        for (int cp = 0; cp < CC; ++cp) tcol[cp] = trL[cp * CC + cc];

        float st = lg[cc];
        if (act) stS[l] = st;                       // stS[0]
        float lgt_next = lg[CC + cc];

#pragma unroll 1
        for (int t = 1; t < sl; ++t) {
            float lgt = lgt_next;
            lgt_next = lg[(t + 1) * CC + cc];       // padded row -> safe
            float sc[CC];
#pragma unroll
            for (int cp = 0; cp < CC; ++cp) sc[cp] = RL(st, cp) + tcol[cp];
            float m0 = fmaxf(fmaxf(sc[0], sc[1]), sc[2]);
            float m1 = fmaxf(fmaxf(sc[3], sc[4]), sc[5]);
            float m2 = fmaxf(fmaxf(sc[6], sc[7]), sc[8]);
            float m3 = fmaxf(fmaxf(sc[9], sc[10]), sc[11]);
            float m4 = fmaxf(fmaxf(sc[12], sc[13]), sc[14]);
            float m5 = fmaxf(fmaxf(sc[15], sc[16]), sc[17]);
            float m6 = fmaxf(fmaxf(sc[18], sc[19]), sc[20]);
            float n0 = fmaxf(fmaxf(m0, m1), m2);
            float n1 = fmaxf(fmaxf(m3, m4), m5);
            float best = fmaxf(fmaxf(n0, n1), m6);
            st = best + lgt;
            if (act) stS[t * CC + l] = st;
        }

        // last_tag = first-max over final state (wave-uniform via readlane)
        float fs[CC];
#pragma unroll
        for (int cp = 0; cp < CC; ++cp) fs[cp] = RL(st, cp);
        float q0 = fmaxf(fmaxf(fs[0], fs[1]), fs[2]);
        float q1 = fmaxf(fmaxf(fs[3], fs[4]), fs[5]);
        float q2 = fmaxf(fmaxf(fs[6], fs[7]), fs[8]);
        float q3 = fmaxf(fmaxf(fs[9], fs[10]), fs[11]);
        float q4 = fmaxf(fmaxf(fs[12], fs[13]), fs[14]);
        float q5 = fmaxf(fmaxf(fs[15], fs[16]), fs[17]);
        float q6 = fmaxf(fmaxf(fs[18], fs[19]), fs[20]);
        float fbest = fmaxf(fmaxf(fmaxf(q0, q1), fmaxf(q2, q3)),
                            fmaxf(fmaxf(q4, q5), q6));
        int e[CC];
#pragma unroll
        for (int cp = 0; cp < CC; ++cp) e[cp] = (fs[cp] == fbest) ? cp : 63;
        int i0 = min(min(e[0], e[1]), e[2]);
        int i1 = min(min(e[3], e[4]), e[5]);
        int i2 = min(min(e[6], e[7]), e[8]);
        int i3 = min(min(e[9], e[10]), e[11]);
        int i4 = min(min(e[12], e[13]), e[14]);
        int i5 = min(min(e[15], e[16]), e[17]);
        int i6 = min(min(e[18], e[19]), e[20]);
        int last = min(min(min(i0, i1), min(i2, i3)), min(min(i4, i5), i6));
        if (l == 0) tagl[TT - 1] = (unsigned char)last;
    } else {
        // ---- identity backpointers for p in [idstart, TT) (invalid steps) ----
        int s = (w - 1) * 64 + l;                  // 0..191
        if (s < 189) {
            int c0 = s % CC, prow = s / CC;        // 9 rows/pass
#pragma unroll 1
            for (int p = idstart + prow; p < TT; p += 9)
                bp[p * CC + c0] = (unsigned char)c0;
        }
    }
    __syncthreads();

    // ---- parallel bp recompute for valid steps t in [1, sl) ----
    if (tid < 252) {
        const int c0 = tid % CC, tg = tid / CC;    // 12 rows/pass
        float tc[CC];
#pragma unroll
        for (int cp = 0; cp < CC; ++cp) tc[cp] = trL[cp * CC + c0];
#pragma unroll 1
        for (int t = 1 + tg; t < sl; t += 12) {
            const float* sp = stS + (t - 1) * CC;
            float bv = sp[0] + tc[0];
            int bi = 0;
#pragma unroll
            for (int cp = 1; cp < CC; ++cp) {
                float v = sp[cp] + tc[cp];
                bool g = v > bv;                   // strict >: first-max kept
                bv = g ? v : bv;
                bi = g ? cp : bi;
            }
            bp[(t - 1) * CC + c0] = (unsigned char)bi;
        }
    }
    __syncthreads();

    // ---- Phase A: candidate maps for 8 chunks of 64 steps ----
    if (tid < 168) {
        int g = tid / CC, cand = tid % CC;
        int startp = (g == 7) ? (TT - 2) : (64 * g + 63);
        int endp = 64 * g;
        int m = cand;
#pragma unroll 1
        for (int i = 0; i < 64; ++i) {
            int p = startp - i;
            int pr = (p >= endp) ? p : endp;
            int m2 = bp[pr * CC + m];
            m = (p >= endp) ? m2 : m;
        }
        mapl[g * CC + cand] = (unsigned char)m;
    }
    __syncthreads();

    // ---- Phase B: compose boundary tags (single thread) ----
    if (tid == 0) {
        int eb = tagl[TT - 1];
        bnd[8] = (unsigned char)eb;
        for (int g = 7; g >= 0; --g) {
            eb = mapl[g * CC + eb];
            bnd[g] = (unsigned char)eb;
        }
    }
    __syncthreads();

    // ---- Phase C: replay 8 chunks in parallel -> full tag sequence ----
    if (tid < 8) {
        int g = tid;
        int startp = (g == 7) ? (TT - 2) : (64 * g + 63);
        int endp = 64 * g;
        int eb = bnd[g + 1];
#pragma unroll 1
        for (int p = startp; p >= endp; --p) {
            eb = bp[p * CC + eb];
            tagl[p] = (unsigned char)eb;
        }
    }
    __syncthreads();

    // ---- Phase D: one-hot write ----
    if (tid < 252) {
        const int c0 = tid % CC, prow = tid / CC;  // 12 rows/pass
        float* ob = onehot + (size_t)b * TT * CC;
#pragma unroll 1
        for (int p = prow; p < TT; p += 12)
            ob[(size_t)p * CC + c0] = (c0 == (int)tagl[p]) ? 1.f : 0.f;
    }
}

extern "C" void kernel_launch(void* const* d_in, const int* in_sizes, int n_in,
                              void* d_out, int out_size, void* d_ws, size_t ws_size,
                              hipStream_t stream) {
    const float* seq   = (const float*)d_in[0];  // [B,T,H] f32
    const int*   msk   = (const int*)d_in[1];    // [B,T] i32
    const float* W     = (const float*)d_in[2];  // [H,C] f32
    const float* bias  = (const float*)d_in[3];  // [C] f32
    const float* trans = (const float*)d_in[4];  // [C,C] f32

    float* onehot_out = (float*)d_out;                     // output 0: [B,T,C]
    float* logits_out = onehot_out + (size_t)BB * TT * CC; // output 1: [B,T,C]

    logits_kernel<<<512, 256, 0, stream>>>(seq, W, bias, logits_out);
    viterbi_kernel<<<BB, 256, 0, stream>>>(logits_out, msk, trans, onehot_out);
}

// Round 5
// 131.330 us; speedup vs baseline: 5.0277x; 1.1373x over previous
//
#include <hip/hip_runtime.h>
#include <stdint.h>

#define BB 64
#define TT 512
#define HH 1024
#define CC 21

#define GAS __attribute__((address_space(1)))
#define LAS __attribute__((address_space(3)))
// async global->LDS, 16B per lane, dest = wave-uniform base + lane*16,
// SOURCE address is per-lane (this is how we transpose for free).
__device__ __forceinline__ void gll16(const void* g, void* l) {
    __builtin_amdgcn_global_load_lds((const GAS uint32_t*)g, (LAS uint32_t*)l, 16, 0, 0);
}

#define RL(x, lane) __uint_as_float(__builtin_amdgcn_readlane(__float_as_uint(x), (lane)))

// ---------------------------------------------------------------------------
// K1: logits = seq @ W + b.  512 blocks x 256 threads; wave w owns h-quarter
// [w*256,+256) of the block's 64 rows; 16 chunks of 16 h.
// X: global_load_lds with per-lane source = seq[row0+l][h0+it*4] into linear
//    slot it*64+l  ->  LDS layout [quad][row]; compute ds_read_b128 at
//    g*64+l is dense contiguous 1024B/wave (conflict-free). No staging regs.
// W: 6 per-lane loads -> padded LDS [16][24] (aligned b128 uniform broadcast).
// Pipeline: X depth-2 (triple buffer), W depth-1 (L2-hot), counted
// s_waitcnt vmcnt(4) in steady state; NO barriers in the main loop.
// ---------------------------------------------------------------------------
__global__ __launch_bounds__(256) void logits_kernel(
    const float* __restrict__ seq,   // [B*T, H]
    const float* __restrict__ W,     // [H, C]
    const float* __restrict__ bias,  // [C]
    float* __restrict__ logits)      // [B*T, C]
{
    __shared__ __align__(16) float4 xsh[4][3][256];    // 48 KB [wave][buf][slot]
    __shared__ __align__(16) float  wsh[4][2][16*24];  // 12 KB [wave][buf][h*24+c]

    const int t = threadIdx.x;
    const int w = t >> 6;          // h-quarter
    const int l = t & 63;          // row within block
    const int row0 = blockIdx.x * 64;
    const int hbase = w * 256;
    const float* seqrow = seq + (size_t)(row0 + l) * HH + hbase;  // per-lane row

    float acc[CC];
#pragma unroll
    for (int c = 0; c < CC; ++c) acc[c] = 0.f;

    float wr[6];

    auto issueX = [&](int ch) {
        float4* dst = xsh[w][ch % 3];
#pragma unroll
        for (int it = 0; it < 4; ++it)
            gll16(seqrow + ch * 16 + it * 4, dst + it * 64);
    };
    auto issueW = [&](int ch) {
        const float* wg = W + (size_t)(hbase + ch * 16) * CC;  // 336 contiguous
#pragma unroll
        for (int i = 0; i < 6; ++i) {
            int j = i * 64 + l;
            wr[i] = (j < 16 * CC) ? wg[j] : 0.f;
        }
    };
    auto commitW = [&](int ch) {
        float* wb = wsh[w][ch & 1];
#pragma unroll
        for (int i = 0; i < 6; ++i) {
            int j = i * 64 + l;
            if (j < 16 * CC) wb[(j / CC) * 24 + (j % CC)] = wr[i];
        }
    };
    auto compute = [&](int ch) {
        const float4* xb = xsh[w][ch % 3];
        const float*  wb = wsh[w][ch & 1];
        float4 xq[4];
#pragma unroll
        for (int q = 0; q < 4; ++q) xq[q] = xb[q * 64 + l];  // dense b128
#pragma unroll
        for (int q = 0; q < 4; ++q) {
#pragma unroll
            for (int j = 0; j < 4; ++j) {
                const float4* wrow = (const float4*)(wb + (q * 4 + j) * 24);
                float xc = (&xq[q].x)[j];
#pragma unroll
                for (int r5 = 0; r5 < 6; ++r5) {   // uniform addr -> broadcast
                    float4 w4 = wrow[r5];
                    int c0 = r5 * 4;
                    acc[c0] += xc * w4.x;
                    if (c0 + 1 < CC) acc[c0 + 1] += xc * w4.y;
                    if (c0 + 2 < CC) acc[c0 + 2] += xc * w4.z;
                    if (c0 + 3 < CC) acc[c0 + 3] += xc * w4.w;
                }
            }
        }
    };

    // prologue: X0, W0, X1 in flight; wait X0+W0 (leave X1's 4 outstanding)
    issueX(0);
    issueW(0);
    issueX(1);
    asm volatile("s_waitcnt vmcnt(4)" ::: "memory");
    commitW(0);

#pragma unroll 1
    for (int ch = 0; ch < 14; ++ch) {
        issueW(ch + 1);                 // FIFO: [X(ch+1)][W(ch+1)][X(ch+2)]
        issueX(ch + 2);
        compute(ch);
        asm volatile("s_waitcnt vmcnt(4)" ::: "memory");  // X,W(ch+1) done
        commitW(ch + 1);
    }
    // ch = 14
    issueW(15);
    compute(14);
    asm volatile("s_waitcnt vmcnt(0)" ::: "memory");
    commitW(15);
    // ch = 15
    compute(15);

    // combine h-quarters; scratch aliased onto xsh (16.9 KB <= 48 KB)
    __syncthreads();
    float* comb = (float*)&xsh[0][0][0];
    if (w > 0) {
        float* cr = comb + ((w - 1) * 64 + l) * 22;
#pragma unroll
        for (int c = 0; c < CC; ++c) cr[c] = acc[c];
    }
    __syncthreads();
    if (w == 0) {
        const float* p0 = comb + (size_t)l * 22;
        const float* p1 = comb + (size_t)(64 + l) * 22;
        const float* p2 = comb + (size_t)(128 + l) * 22;
        float* orow = logits + (size_t)(row0 + l) * CC;
#pragma unroll
        for (int c = 0; c < CC; ++c)
            orow[c] = acc[c] + p0[c] + p1[c] + p2[c] + bias[c];
    }
}

// ---------------------------------------------------------------------------
// K2: Viterbi. One block (256 threads) per batch. Wave 0: serial forward scan
// with minimal chain (21 readlane+add, max3 tree, add), storing state history.
// Backpointers recomputed in parallel (bit-exact). Backtrack via 12 chunked
// candidate pointer-maps of 43 steps (integer, exact). One-hot by 252 threads.
// ---------------------------------------------------------------------------
__global__ __launch_bounds__(256) void viterbi_kernel(
    const float* __restrict__ logits,  // [B, T, C]
    const int* __restrict__ mask,      // [B, T]
    const float* __restrict__ trans,   // [C, C]
    float* __restrict__ onehot)        // [B, T, C]
{
    __shared__ __align__(16) float lg[(TT + 1) * CC];   // +1 row: prefetch pad
    __shared__ float stS[TT * CC];
    __shared__ float trL[CC * CC];
    __shared__ unsigned char bp[TT * CC];
    __shared__ unsigned char tagl[TT];
    __shared__ unsigned char mapl[12 * CC];
    __shared__ unsigned char bnd[13];

    const int tid = threadIdx.x;
    const int w = tid >> 6;
    const int l = tid & 63;
    const int b = blockIdx.x;

    // stage logits[b] -> LDS
    const float* lb = logits + (size_t)b * TT * CC;
    for (int i = w; i < 42; i += 4)
        gll16(lb + (size_t)(i * 64 + l) * 4, &lg[i * 256]);

    for (int j = tid; j < CC * CC; j += 256) trL[j] = trans[j];

    int sl = 0;
#pragma unroll
    for (int k = 0; k < 8; ++k) sl += mask[b * TT + k * 64 + l];
#pragma unroll
    for (int o = 32; o > 0; o >>= 1) sl += __shfl_xor(sl, o);
    const int idstart = (sl >= 1) ? (sl - 1) : 0;

    asm volatile("s_waitcnt vmcnt(0)" ::: "memory");
    __syncthreads();

    if (w == 0) {
        // ---- forward scan ----
        const bool act = (l < CC);
        const int cc = act ? l : 0;
        float tcol[CC];
#pragma unroll
        for (int cp = 0; cp < CC; ++cp) tcol[cp] = trL[cp * CC + cc];

        float st = lg[cc];
        if (act) stS[l] = st;
        float lgt_next = lg[CC + cc];

#pragma unroll 1
        for (int t = 1; t < sl; ++t) {
            float lgt = lgt_next;
            lgt_next = lg[(t + 1) * CC + cc];
            float sc[CC];
#pragma unroll
            for (int cp = 0; cp < CC; ++cp) sc[cp] = RL(st, cp) + tcol[cp];
            float m0 = fmaxf(fmaxf(sc[0], sc[1]), sc[2]);
            float m1 = fmaxf(fmaxf(sc[3], sc[4]), sc[5]);
            float m2 = fmaxf(fmaxf(sc[6], sc[7]), sc[8]);
            float m3 = fmaxf(fmaxf(sc[9], sc[10]), sc[11]);
            float m4 = fmaxf(fmaxf(sc[12], sc[13]), sc[14]);
            float m5 = fmaxf(fmaxf(sc[15], sc[16]), sc[17]);
            float m6 = fmaxf(fmaxf(sc[18], sc[19]), sc[20]);
            float n0 = fmaxf(fmaxf(m0, m1), m2);
            float n1 = fmaxf(fmaxf(m3, m4), m5);
            float best = fmaxf(fmaxf(n0, n1), m6);
            st = best + lgt;
            if (act) stS[t * CC + l] = st;
        }

        // last_tag = first-max over final state
        float fs[CC];
#pragma unroll
        for (int cp = 0; cp < CC; ++cp) fs[cp] = RL(st, cp);
        float q0 = fmaxf(fmaxf(fs[0], fs[1]), fs[2]);
        float q1 = fmaxf(fmaxf(fs[3], fs[4]), fs[5]);
        float q2 = fmaxf(fmaxf(fs[6], fs[7]), fs[8]);
        float q3 = fmaxf(fmaxf(fs[9], fs[10]), fs[11]);
        float q4 = fmaxf(fmaxf(fs[12], fs[13]), fs[14]);
        float q5 = fmaxf(fmaxf(fs[15], fs[16]), fs[17]);
        float q6 = fmaxf(fmaxf(fs[18], fs[19]), fs[20]);
        float fbest = fmaxf(fmaxf(fmaxf(q0, q1), fmaxf(q2, q3)),
                            fmaxf(fmaxf(q4, q5), q6));
        int e[CC];
#pragma unroll
        for (int cp = 0; cp < CC; ++cp) e[cp] = (fs[cp] == fbest) ? cp : 63;
        int i0 = min(min(e[0], e[1]), e[2]);
        int i1 = min(min(e[3], e[4]), e[5]);
        int i2 = min(min(e[6], e[7]), e[8]);
        int i3 = min(min(e[9], e[10]), e[11]);
        int i4 = min(min(e[12], e[13]), e[14]);
        int i5 = min(min(e[15], e[16]), e[17]);
        int i6 = min(min(e[18], e[19]), e[20]);
        int last = min(min(min(i0, i1), min(i2, i3)), min(min(i4, i5), i6));
        if (l == 0) tagl[TT - 1] = (unsigned char)last;
    } else {
        // identity backpointers for p in [idstart, TT)
        int s = (w - 1) * 64 + l;                  // 0..191
        if (s < 189) {
            int c0 = s % CC, prow = s / CC;        // 9 rows/pass
#pragma unroll 1
            for (int p = idstart + prow; p < TT; p += 9)
                bp[p * CC + c0] = (unsigned char)c0;
        }
    }
    __syncthreads();

    // ---- parallel bp recompute for valid steps ----
    if (tid < 252) {
        const int c0 = tid % CC, tg = tid / CC;    // 12 rows/pass
        float tc[CC];
#pragma unroll
        for (int cp = 0; cp < CC; ++cp) tc[cp] = trL[cp * CC + c0];
#pragma unroll 1
        for (int t = 1 + tg; t < sl; t += 12) {
            const float* sp = stS + (t - 1) * CC;
            float bv = sp[0] + tc[0];
            int bi = 0;
#pragma unroll
            for (int cp = 1; cp < CC; ++cp) {
                float v = sp[cp] + tc[cp];
                bool g = v > bv;                   // strict >: first-max
                bv = g ? v : bv;
                bi = g ? cp : bi;
            }
            bp[(t - 1) * CC + c0] = (unsigned char)bi;
        }
    }
    __syncthreads();

    // ---- Phase A: candidate maps for 12 chunks of 43 steps ----
    if (tid < 252) {
        int g = tid / CC, cand = tid % CC;
        int endp = g * 43;
        int startp = min(g * 43 + 42, TT - 2);
        int m = cand;
#pragma unroll 1
        for (int i = 0; i < 43; ++i) {
            int p = startp - i;
            int pr = (p >= endp) ? p : endp;
            int m2 = bp[pr * CC + m];
            m = (p >= endp) ? m2 : m;
        }
        mapl[g * CC + cand] = (unsigned char)m;
    }
    __syncthreads();

    // ---- Phase B: compose boundary tags ----
    if (tid == 0) {
        int eb = tagl[TT - 1];
        bnd[12] = (unsigned char)eb;
        for (int g = 11; g >= 0; --g) {
            eb = mapl[g * CC + eb];
            bnd[g] = (unsigned char)eb;
        }
    }
    __syncthreads();

    // ---- Phase C: replay 12 chunks in parallel ----
    if (tid < 12) {
        int g = tid;
        int endp = g * 43;
        int startp = min(g * 43 + 42, TT - 2);
        int eb = bnd[g + 1];
#pragma unroll 1
        for (int p = startp; p >= endp; --p) {
            eb = bp[p * CC + eb];
            tagl[p] = (unsigned char)eb;
        }
    }
    __syncthreads();

    // ---- Phase D: one-hot write ----
    if (tid < 252) {
        const int c0 = tid % CC, prow = tid / CC;
        float* ob = onehot + (size_t)b * TT * CC;
#pragma unroll 1
        for (int p = prow; p < TT; p += 12)
            ob[(size_t)p * CC + c0] = (c0 == (int)tagl[p]) ? 1.f : 0.f;
    }
}

extern "C" void kernel_launch(void* const* d_in, const int* in_sizes, int n_in,
                              void* d_out, int out_size, void* d_ws, size_t ws_size,
                              hipStream_t stream) {
    const float* seq   = (const float*)d_in[0];  // [B,T,H] f32
    const int*   msk   = (const int*)d_in[1];    // [B,T] i32
    const float* W     = (const float*)d_in[2];  // [H,C] f32
    const float* bias  = (const float*)d_in[3];  // [C] f32
    const float* trans = (const float*)d_in[4];  // [C,C] f32

    float* onehot_out = (float*)d_out;                     // output 0: [B,T,C]
    float* logits_out = onehot_out + (size_t)BB * TT * CC; // output 1: [B,T,C]

    logits_kernel<<<512, 256, 0, stream>>>(seq, W, bias, logits_out);
    viterbi_kernel<<<BB, 256, 0, stream>>>(logits_out, msk, trans, onehot_out);
}